// Round 1
// baseline (237.916 us; speedup 1.0000x reference)
//
#include <hip/hip_runtime.h>
#include <math.h>

#define HH 256
#define WW 256
#define NB 4
#define NG 1024      // gaussians per batch
#define DD 768

#if __has_builtin(__builtin_amdgcn_exp2f)
#define EXP2(x) __builtin_amdgcn_exp2f(x)
#else
#define EXP2(x) exp2f(x)
#endif

// params layout per gaussian: 12 floats (3x float4), 16B aligned:
//  [0]=px [1]=py [2]=e00 [3]=e01 [4]=e11 [5]=log2(alpha) [6]=c0 [7]=c1 [8]=c2 [9..11]=pad
// where e00 = -0.5*log2e*i00, e01 = -log2e*i01 (2x folded), e11 = -0.5*log2e*i11
// so weight = exp2(e00*dx^2 + e01*dx*dy + e11*dy^2 + log2(alpha))

__global__ __launch_bounds__(256) void param_kernel(
    const float* __restrict__ feature, const float* __restrict__ proj_w,
    const float* __restrict__ proj_b, float* __restrict__ params)
{
    __shared__ float frow[DD];
    __shared__ float gsv[36];
    const int bt  = blockIdx.x;          // 0..1023 ; b = bt>>8, t = bt&255
    const int tid = threadIdx.x;

    // stage this row's feature vector in LDS (768 f32 = 3 KB)
    if (tid < DD / 4) {
        ((float4*)frow)[tid] = ((const float4*)(feature + bt * DD))[tid];
    }
    __syncthreads();

    const int wave = tid >> 6, lane = tid & 63;
    // 4 waves x 9 outputs = 36 projections
    for (int i = 0; i < 9; ++i) {
        const int k = wave * 9 + i;
        const float* wrow = proj_w + k * DD;
        float s = 0.f;
        #pragma unroll
        for (int j = 0; j < DD / 64; ++j)
            s = fmaf(frow[lane + j * 64], wrow[lane + j * 64], s);
        #pragma unroll
        for (int off = 32; off; off >>= 1) s += __shfl_xor(s, off, 64);
        if (lane == 0) gsv[k] = s + proj_b[k];
    }
    __syncthreads();

    if (tid < 4) {
        const float* g = gsv + tid * 9;
        const float px = g[0], py = g[1];
        const float sx = expf(g[2]), sy = expf(g[3]);
        const float sx2 = sx * sx, sy2 = sy * sy;
        const float cs = cosf(g[4]), sn = sinf(g[4]);
        const float c00 = cs * cs * sx2 + sn * sn * sy2 + 1e-6f;
        const float c01 = cs * sn * (sx2 - sy2);
        const float c11 = sn * sn * sx2 + cs * cs * sy2 + 1e-6f;
        const float det = c00 * c11 - c01 * c01;
        const float i00 = c11 / det, i01 = -c01 / det, i11 = c00 / det;
        const float F = 0.72134752044448170368f;   // 0.5 * log2(e)
        const float e00 = -F * i00;
        const float e01 = -2.f * F * i01;
        const float e11 = -F * i11;
        // log2(sigmoid(x)) = -log2(1 + exp(-x))
        const float la = -log2f(1.f + expf(-g[5]));
        float* o = params + (bt * 4 + tid) * 12;    // == (b*NG + n_local)*12
        o[0] = px;  o[1] = py;  o[2] = e00; o[3] = e01;
        o[4] = e11; o[5] = la;  o[6] = g[6]; o[7] = g[7];
        o[8] = g[8]; o[9] = 0.f; o[10] = 0.f; o[11] = 0.f;
    }
}

// 512 blocks x 256 threads. Block = (batch, 2 rows). Thread owns 2 pixels in
// one row (x and x+128); dy-dependent terms hoisted per gaussian.
__global__ __launch_bounds__(256) void splat_kernel(
    const float* __restrict__ params, float* __restrict__ out)
{
    const int blk = blockIdx.x;
    const int b   = blk >> 7;              // 128 blocks per batch
    const int y0  = (blk & 127) * 2;
    const int tid = threadIdx.x;
    const int ry  = tid >> 7;              // 0/1: which row of the pair
    const int x0  = tid & 127;
    const int y   = y0 + ry;

    const float s2 = 2.f / 255.f;
    const float yg  = -1.f + s2 * (float)y;
    const float xgA = -1.f + s2 * (float)x0;
    const float xgB = -1.f + s2 * (float)(x0 + 128);

    const float* gp = params + b * NG * 12;

    float rA0 = 0.f, rA1 = 0.f, rA2 = 0.f, wAs = 0.f;
    float rB0 = 0.f, rB1 = 0.f, rB2 = 0.f, wBs = 0.f;

    #pragma unroll 2
    for (int g = 0; g < NG; ++g) {
        const float4 p0 = ((const float4*)(gp + g * 12))[0];
        const float4 p1 = ((const float4*)(gp + g * 12))[1];
        const float  c2 = gp[g * 12 + 8];

        const float dy = yg - p0.y;
        const float kd = p0.w * dy;                   // e01*dy
        const float kc = fmaf(p1.x * dy, dy, p1.y);   // e11*dy^2 + la

        const float dxA = xgA - p0.x;
        const float qA  = fmaf(dxA, fmaf(p0.z, dxA, kd), kc);
        const float w1  = EXP2(qA);
        wAs += w1;
        rA0 = fmaf(w1, p1.z, rA0);
        rA1 = fmaf(w1, p1.w, rA1);
        rA2 = fmaf(w1, c2,   rA2);

        const float dxB = xgB - p0.x;
        const float qB  = fmaf(dxB, fmaf(p0.z, dxB, kd), kc);
        const float w2  = EXP2(qB);
        wBs += w2;
        rB0 = fmaf(w2, p1.z, rB0);
        rB1 = fmaf(w2, p1.w, rB1);
        rB2 = fmaf(w2, c2,   rB2);
    }

    const float invA = 1.f / (wAs + 1e-6f);
    const float invB = 1.f / (wBs + 1e-6f);

    float* ob = out + (b * 3) * (HH * WW) + y * WW;
    ob[0 * HH * WW + x0]       = rA0 * invA;
    ob[1 * HH * WW + x0]       = rA1 * invA;
    ob[2 * HH * WW + x0]       = rA2 * invA;
    ob[0 * HH * WW + x0 + 128] = rB0 * invB;
    ob[1 * HH * WW + x0 + 128] = rB1 * invB;
    ob[2 * HH * WW + x0 + 128] = rB2 * invB;
}

extern "C" void kernel_launch(void* const* d_in, const int* in_sizes, int n_in,
                              void* d_out, int out_size, void* d_ws, size_t ws_size,
                              hipStream_t stream) {
    const float* feature = (const float*)d_in[0];   // (4,256,768) f32
    const float* proj_w  = (const float*)d_in[1];   // (36,768) f32
    const float* proj_b  = (const float*)d_in[2];   // (36,) f32
    float* params = (float*)d_ws;                   // 4096*12 f32 = 196 KB
    float* out    = (float*)d_out;                  // (4,3,256,256) f32

    param_kernel<<<NB * 256, 256, 0, stream>>>(feature, proj_w, proj_b, params);
    splat_kernel<<<NB * 128, 256, 0, stream>>>(params, out);
}

// Round 4
// 149.587 us; speedup vs baseline: 1.5905x; 1.5905x over previous
//
#include <hip/hip_runtime.h>
#include <math.h>

#define HH 256
#define WW 256
#define NB 4
#define NG 1024      // gaussians per batch
#define DD 768
#define SPLIT 4
#define GPER (NG / SPLIT)     // 256 gaussians per subgroup
#define GCHUNK 128            // gaussians staged to LDS per stage
#define NSTAGE (GPER / GCHUNK)

#if __has_builtin(__builtin_amdgcn_exp2f)
#define EXP2(x) __builtin_amdgcn_exp2f(x)
#else
#define EXP2(x) exp2f(x)
#endif

// params layout per gaussian: 12 floats (3x float4), 16B aligned:
//  [0]=px [1]=py [2]=e00 [3]=e01 [4]=e11 [5]=log2(alpha) [6]=c0 [7]=c1 [8]=c2 [9..11]=pad
// weight = exp2(e00*dx^2 + e01*dx*dy + e11*dy^2 + log2(alpha))

__global__ __launch_bounds__(256) void param_kernel(
    const float* __restrict__ feature, const float* __restrict__ proj_w,
    const float* __restrict__ proj_b, float* __restrict__ params)
{
    __shared__ float frow[DD];
    __shared__ float gsv[36];
    const int bt  = blockIdx.x;          // 0..1023 ; b = bt>>8, t = bt&255
    const int tid = threadIdx.x;

    if (tid < DD / 4) {
        ((float4*)frow)[tid] = ((const float4*)(feature + bt * DD))[tid];
    }
    __syncthreads();

    const int wave = tid >> 6, lane = tid & 63;
    for (int i = 0; i < 9; ++i) {
        const int k = wave * 9 + i;
        const float* wrow = proj_w + k * DD;
        float s = 0.f;
        #pragma unroll
        for (int j = 0; j < DD / 64; ++j)
            s = fmaf(frow[lane + j * 64], wrow[lane + j * 64], s);
        #pragma unroll
        for (int off = 32; off; off >>= 1) s += __shfl_xor(s, off, 64);
        if (lane == 0) gsv[k] = s + proj_b[k];
    }
    __syncthreads();

    if (tid < 4) {
        const float* g = gsv + tid * 9;
        const float px = g[0], py = g[1];
        const float sx = expf(g[2]), sy = expf(g[3]);
        const float sx2 = sx * sx, sy2 = sy * sy;
        const float cs = cosf(g[4]), sn = sinf(g[4]);
        const float c00 = cs * cs * sx2 + sn * sn * sy2 + 1e-6f;
        const float c01 = cs * sn * (sx2 - sy2);
        const float c11 = sn * sn * sx2 + cs * cs * sy2 + 1e-6f;
        const float det = c00 * c11 - c01 * c01;
        const float i00 = c11 / det, i01 = -c01 / det, i11 = c00 / det;
        const float F = 0.72134752044448170368f;   // 0.5 * log2(e)
        const float e00 = -F * i00;
        const float e01 = -2.f * F * i01;
        const float e11 = -F * i11;
        const float la = -log2f(1.f + expf(-g[5]));   // log2(sigmoid)
        float* o = params + (bt * 4 + tid) * 12;
        o[0] = px;  o[1] = py;  o[2] = e00; o[3] = e01;
        o[4] = e11; o[5] = la;  o[6] = g[6]; o[7] = g[7];
        o[8] = g[8]; o[9] = 0.f; o[10] = 0.f; o[11] = 0.f;
    }
}

// 512 blocks x 1024 threads. Block = (batch, 2 rows) = 512 pixels.
// 4 subgroups of 256 threads each handle a disjoint quarter of the gaussians
// for the SAME 512 pixels; partials combined through LDS at the end.
// Thread t in a subgroup owns pixels (x0, x0+128) of row y0 + (t>>7).
__global__ __launch_bounds__(1024, 8) void splat_kernel(
    const float* __restrict__ params, float* __restrict__ out)
{
    __shared__ float stg[SPLIT][GCHUNK * 12];   // 24 KB staging
    __shared__ float red[SPLIT - 1][8][256];    // 24 KB reduce

    const int blk = blockIdx.x;
    const int b   = blk >> 7;              // 128 blocks per batch
    const int y0  = (blk & 127) * 2;
    const int tid = threadIdx.x;
    const int sub = tid >> 8;              // gaussian quarter 0..3
    const int t   = tid & 255;
    const int ry  = t >> 7;
    const int x0  = t & 127;
    const int y   = y0 + ry;

    const float s2  = 2.f / 255.f;
    const float yg  = -1.f + s2 * (float)y;
    const float xgA = -1.f + s2 * (float)x0;
    const float xgB = -1.f + s2 * (float)(x0 + 128);

    const float* gbase = params + (b * NG + sub * GPER) * 12;

    float rA0 = 0.f, rA1 = 0.f, rA2 = 0.f, wAs = 0.f;
    float rB0 = 0.f, rB1 = 0.f, rB2 = 0.f, wBs = 0.f;

    for (int st = 0; st < NSTAGE; ++st) {
        __syncthreads();                   // previous chunk fully consumed
        const float4* src = (const float4*)(gbase + st * GCHUNK * 12);
        float4*       dst = (float4*)stg[sub];
        for (int i = t; i < GCHUNK * 3; i += 256) dst[i] = src[i];
        __syncthreads();                   // chunk staged

        #pragma unroll 2
        for (int g = 0; g < GCHUNK; ++g) {
            const float* p = stg[sub] + g * 12;
            const float px = p[0], py = p[1], e00 = p[2], e01 = p[3];
            const float e11 = p[4], la = p[5], c0 = p[6], c1 = p[7], c2 = p[8];

            const float dy = yg - py;
            const float kd = e01 * dy;
            const float kc = fmaf(e11 * dy, dy, la);

            const float dxA = xgA - px;
            const float qA  = fmaf(dxA, fmaf(e00, dxA, kd), kc);
            const float w1  = EXP2(qA);
            wAs += w1;
            rA0 = fmaf(w1, c0, rA0);
            rA1 = fmaf(w1, c1, rA1);
            rA2 = fmaf(w1, c2, rA2);

            const float dxB = xgB - px;
            const float qB  = fmaf(dxB, fmaf(e00, dxB, kd), kc);
            const float w2  = EXP2(qB);
            wBs += w2;
            rB0 = fmaf(w2, c0, rB0);
            rB1 = fmaf(w2, c1, rB1);
            rB2 = fmaf(w2, c2, rB2);
        }
    }

    if (sub != 0) {
        float acc[8] = { rA0, rA1, rA2, wAs, rB0, rB1, rB2, wBs };
        #pragma unroll
        for (int c = 0; c < 8; ++c) red[sub - 1][c][t] = acc[c];
    }
    __syncthreads();
    if (sub == 0) {
        float acc[8] = { rA0, rA1, rA2, wAs, rB0, rB1, rB2, wBs };
        #pragma unroll
        for (int s = 0; s < SPLIT - 1; ++s)
            #pragma unroll
            for (int c = 0; c < 8; ++c) acc[c] += red[s][c][t];

        const float invA = 1.f / (acc[3] + 1e-6f);
        const float invB = 1.f / (acc[7] + 1e-6f);

        float* ob = out + (b * 3) * (HH * WW) + y * WW;
        ob[0 * HH * WW + x0]       = acc[0] * invA;
        ob[1 * HH * WW + x0]       = acc[1] * invA;
        ob[2 * HH * WW + x0]       = acc[2] * invA;
        ob[0 * HH * WW + x0 + 128] = acc[4] * invB;
        ob[1 * HH * WW + x0 + 128] = acc[5] * invB;
        ob[2 * HH * WW + x0 + 128] = acc[6] * invB;
    }
}

extern "C" void kernel_launch(void* const* d_in, const int* in_sizes, int n_in,
                              void* d_out, int out_size, void* d_ws, size_t ws_size,
                              hipStream_t stream) {
    const float* feature = (const float*)d_in[0];   // (4,256,768) f32
    const float* proj_w  = (const float*)d_in[1];   // (36,768) f32
    const float* proj_b  = (const float*)d_in[2];   // (36,) f32
    float* params = (float*)d_ws;                   // 4096*12 f32 = 196 KB
    float* out    = (float*)d_out;                  // (4,3,256,256) f32

    param_kernel<<<NB * 256, 256, 0, stream>>>(feature, proj_w, proj_b, params);
    splat_kernel<<<NB * 128, 1024, 0, stream>>>(params, out);
}

// Round 6
// 133.691 us; speedup vs baseline: 1.7796x; 1.1189x over previous
//
#include <hip/hip_runtime.h>
#include <math.h>

#define HH 256
#define WW 256
#define NB 4
#define NG 1024      // gaussians per batch
#define DD 768
#define TH_CULL 42.0f   // cull if best-case weight exponent < -42 (err <= ~5e-4)

#if __has_builtin(__builtin_amdgcn_exp2f)
#define EXP2(x) __builtin_amdgcn_exp2f(x)
#else
#define EXP2(x) exp2f(x)
#endif

// params layout per gaussian: 12 floats (3x float4), 16B aligned:
//  [0]=px [1]=py [2]=e00 [3]=e01 [4]=e11 [5]=log2(alpha) [6]=c0 [7]=c1 [8]=c2
//  [9]=sqrt(-(e00+e11))  (>= sqrt(lambda_max) of the positive form, for culling)
// weight = exp2(e00*dx^2 + e01*dx*dy + e11*dy^2 + log2(alpha)), e's < 0.

__global__ __launch_bounds__(256) void param_kernel(
    const float* __restrict__ feature, const float* __restrict__ proj_w,
    const float* __restrict__ proj_b, float* __restrict__ params)
{
    __shared__ float frow[DD];
    __shared__ float gsv[36];
    const int bt  = blockIdx.x;          // 0..1023
    const int tid = threadIdx.x;

    if (tid < DD / 4) {
        ((float4*)frow)[tid] = ((const float4*)(feature + bt * DD))[tid];
    }
    __syncthreads();

    const int wave = tid >> 6, lane = tid & 63;
    for (int i = 0; i < 9; ++i) {
        const int k = wave * 9 + i;
        const float* wrow = proj_w + k * DD;
        float s = 0.f;
        #pragma unroll
        for (int j = 0; j < DD / 64; ++j)
            s = fmaf(frow[lane + j * 64], wrow[lane + j * 64], s);
        #pragma unroll
        for (int off = 32; off; off >>= 1) s += __shfl_xor(s, off, 64);
        if (lane == 0) gsv[k] = s + proj_b[k];
    }
    __syncthreads();

    if (tid < 4) {
        const float* g = gsv + tid * 9;
        const float px = g[0], py = g[1];
        const float sx = expf(g[2]), sy = expf(g[3]);
        const float sx2 = sx * sx, sy2 = sy * sy;
        const float cs = cosf(g[4]), sn = sinf(g[4]);
        const float c00 = cs * cs * sx2 + sn * sn * sy2 + 1e-6f;
        const float c01 = cs * sn * (sx2 - sy2);
        const float c11 = sn * sn * sx2 + cs * cs * sy2 + 1e-6f;
        const float det = c00 * c11 - c01 * c01;
        const float i00 = c11 / det, i01 = -c01 / det, i11 = c00 / det;
        const float F = 0.72134752044448170368f;   // 0.5 * log2(e)
        const float e00 = -F * i00;
        const float e01 = -2.f * F * i01;
        const float e11 = -F * i11;
        const float la = -log2f(1.f + expf(-g[5]));   // log2(sigmoid)
        float* o = params + (bt * 4 + tid) * 12;
        o[0] = px;  o[1] = py;  o[2] = e00; o[3] = e01;
        o[4] = e11; o[5] = la;  o[6] = g[6]; o[7] = g[7];
        o[8] = g[8];
        o[9] = sqrtf(-(e00 + e11));   // sqrt of trace of positive-definite form
        o[10] = 0.f; o[11] = 0.f;
    }
}

// One block per 16x16-pixel tile: 4 batches x 256 tiles = 1024 blocks x 256 thr.
// Phase 1: cull+compact the batch's 1024 gaussians against a conservative
//          tile bound into an LDS index list (ballot/popc within each wave,
//          LDS atomic across waves).
// Phase 2: thread = 1 pixel; walk compacted list with scalar (SGPR) param
//          loads via readfirstlane.
__global__ __launch_bounds__(256) void splat_kernel(
    const float* __restrict__ params, float* __restrict__ out)
{
    __shared__ int slist[NG];
    __shared__ int scount;

    const int blk = blockIdx.x;
    const int b   = blk >> 8;            // 256 tiles per batch
    const int tl  = blk & 255;
    const int ty  = tl >> 4, tx = tl & 15;
    const int tid = threadIdx.x;
    const int lane = tid & 63;

    if (tid == 0) scount = 0;
    __syncthreads();

    const float s2 = 2.f / 255.f;
    const float cx = -1.f + s2 * ((float)(tx * 16) + 7.5f);
    const float cy = -1.f + s2 * ((float)(ty * 16) + 7.5f);
    const float rt = s2 * 7.5f * 1.41421356f;   // tile bounding-circle radius

    const float* gp = params + b * NG * 12;

    // ---- phase 1: bin (each thread tests 4 gaussians) ----
    for (int k = 0; k < 4; ++k) {
        const int gi = k * 256 + tid;
        const float4 p0 = *(const float4*)(gp + gi * 12);      // px,py,e00,e01
        const float4 p1 = *(const float4*)(gp + gi * 12 + 4);  // e11,la,c0,c1
        const float rsq = gp[gi * 12 + 9];
        const float dx = cx - p0.x, dy = cy - p0.y;
        const float qd = -(p0.z * dx * dx + p0.w * dx * dy + p1.x * dy * dy);
        const float m  = sqrtf(fmaxf(qd, 0.f));     // ||d||_A (guard NaN at d~0)
        const float u  = m - rt * rsq;              // A-distance beyond tile circle
        const bool keep = (u <= 0.f) || (u * u <= TH_CULL + p1.y);
        const unsigned long long mask = __ballot(keep);
        int base = 0;
        if (lane == 0 && mask) base = atomicAdd(&scount, (int)__popcll(mask));
        base = __shfl(base, 0, 64);
        if (keep) {
            const int off = (int)__popcll(mask & ((1ull << lane) - 1ull));
            slist[base + off] = gi;
        }
    }
    __syncthreads();
    const int cnt = scount;

    // ---- phase 2: splat compacted list ----
    const int py = tid >> 4, px = tid & 15;
    const int X = tx * 16 + px, Y = ty * 16 + py;
    const float xg = -1.f + s2 * (float)X;
    const float yg = -1.f + s2 * (float)Y;

    float r0 = 0.f, r1 = 0.f, r2 = 0.f, ws = 0.f;
    #pragma unroll 2
    for (int g = 0; g < cnt; ++g) {
        const int sidx = __builtin_amdgcn_readfirstlane(slist[g]);
        const float* p = gp + sidx * 12;
        const float dx = xg - p[0];
        const float dy = yg - p[1];
        const float q  = fmaf(dx, fmaf(p[2], dx, p[3] * dy),
                              fmaf(p[4] * dy, dy, p[5]));
        const float w  = EXP2(q);
        ws += w;
        r0 = fmaf(w, p[6], r0);
        r1 = fmaf(w, p[7], r1);
        r2 = fmaf(w, p[8], r2);
    }

    const float inv = 1.f / (ws + 1e-6f);
    float* ob = out + (b * 3) * (HH * WW) + Y * WW + X;
    ob[0]           = r0 * inv;
    ob[HH * WW]     = r1 * inv;
    ob[2 * HH * WW] = r2 * inv;
}

extern "C" void kernel_launch(void* const* d_in, const int* in_sizes, int n_in,
                              void* d_out, int out_size, void* d_ws, size_t ws_size,
                              hipStream_t stream) {
    const float* feature = (const float*)d_in[0];   // (4,256,768) f32
    const float* proj_w  = (const float*)d_in[1];   // (36,768) f32
    const float* proj_b  = (const float*)d_in[2];   // (36,) f32
    float* params = (float*)d_ws;                   // 4096*12 f32 = 196 KB
    float* out    = (float*)d_out;                  // (4,3,256,256) f32

    param_kernel<<<NB * 256, 256, 0, stream>>>(feature, proj_w, proj_b, params);
    splat_kernel<<<NB * 256, 256, 0, stream>>>(params, out);
}

// Round 8
// 111.166 us; speedup vs baseline: 2.1402x; 1.2026x over previous
//
#include <hip/hip_runtime.h>
#include <math.h>

#define HH 256
#define WW 256
#define NB 4
#define NG 1024      // gaussians per batch
#define DD 768
#define TH_CULL 42.0f   // cull if best-case weight exponent < -42 (err <= ~5e-4)
#define TPB 128         // splat threads per block (2 waves)
#define CH 128          // survivors staged to LDS per chunk

#if __has_builtin(__builtin_amdgcn_exp2f)
#define EXP2(x) __builtin_amdgcn_exp2f(x)
#else
#define EXP2(x) exp2f(x)
#endif

// params layout per gaussian: 12 floats (3x float4), 16B aligned:
//  [0]=px [1]=py [2]=e00 [3]=e01 [4]=e11 [5]=log2(alpha) [6]=c0 [7]=c1 [8]=c2
//  [9]=sqrt(-(e00+e11))  (>= sqrt(lambda_max) of positive form, for culling)
// weight = exp2(e00*dx^2 + e01*dx*dy + e11*dy^2 + log2(alpha)), e's < 0.

__global__ __launch_bounds__(256) void param_kernel(
    const float* __restrict__ feature, const float* __restrict__ proj_w,
    const float* __restrict__ proj_b, float* __restrict__ params)
{
    __shared__ float frow[DD];
    __shared__ float gsv[36];
    const int bt  = blockIdx.x;          // 0..1023
    const int tid = threadIdx.x;

    if (tid < DD / 4) {
        ((float4*)frow)[tid] = ((const float4*)(feature + bt * DD))[tid];
    }
    __syncthreads();

    const int wave = tid >> 6, lane = tid & 63;
    for (int i = 0; i < 9; ++i) {
        const int k = wave * 9 + i;
        const float* wrow = proj_w + k * DD;
        float s = 0.f;
        #pragma unroll
        for (int j = 0; j < DD / 64; ++j)
            s = fmaf(frow[lane + j * 64], wrow[lane + j * 64], s);
        #pragma unroll
        for (int off = 32; off; off >>= 1) s += __shfl_xor(s, off, 64);
        if (lane == 0) gsv[k] = s + proj_b[k];
    }
    __syncthreads();

    if (tid < 4) {
        const float* g = gsv + tid * 9;
        const float px = g[0], py = g[1];
        const float sx = expf(g[2]), sy = expf(g[3]);
        const float sx2 = sx * sx, sy2 = sy * sy;
        const float cs = cosf(g[4]), sn = sinf(g[4]);
        const float c00 = cs * cs * sx2 + sn * sn * sy2 + 1e-6f;
        const float c01 = cs * sn * (sx2 - sy2);
        const float c11 = sn * sn * sx2 + cs * cs * sy2 + 1e-6f;
        const float det = c00 * c11 - c01 * c01;
        const float i00 = c11 / det, i01 = -c01 / det, i11 = c00 / det;
        const float F = 0.72134752044448170368f;   // 0.5 * log2(e)
        const float e00 = -F * i00;
        const float e01 = -2.f * F * i01;
        const float e11 = -F * i11;
        const float la = -log2f(1.f + expf(-g[5]));   // log2(sigmoid)
        float* o = params + (bt * 4 + tid) * 12;
        o[0] = px;  o[1] = py;  o[2] = e00; o[3] = e01;
        o[4] = e11; o[5] = la;  o[6] = g[6]; o[7] = g[7];
        o[8] = g[8];
        o[9] = sqrtf(-(e00 + e11));
        o[10] = 0.f; o[11] = 0.f;
    }
}

// 1024 blocks (4 batches x 256 tiles of 16x16 px) x 128 threads (2 waves).
// Thread owns 2 pixels sharing x: (X, Y) and (X, Y+8)  [px=tid&15, py=tid>>4].
// Phase 1: cull+compact survivor indices into LDS slist (ballot/popc).
// Phase 2: chunked: cooperatively gather 128 survivors' params into LDS
//          (parallel independent float4 loads), then walk the chunk with
//          broadcast ds_read_b128 at static offsets — no pointer chasing.
__global__ __launch_bounds__(TPB) void splat_kernel(
    const float* __restrict__ params, float* __restrict__ out)
{
    __shared__ int   slist[NG];        // 4 KB
    __shared__ float sp[CH * 12];      // 6 KB staged params
    __shared__ int   scount;

    const int blk = blockIdx.x;
    const int b   = blk >> 8;            // 256 tiles per batch
    const int tl  = blk & 255;
    const int ty  = tl >> 4, tx = tl & 15;
    const int tid = threadIdx.x;
    const int lane = tid & 63;

    if (tid == 0) scount = 0;
    __syncthreads();

    const float s2 = 2.f / 255.f;
    const float cx = -1.f + s2 * ((float)(tx * 16) + 7.5f);
    const float cy = -1.f + s2 * ((float)(ty * 16) + 7.5f);
    const float rt = s2 * 7.5f * 1.41421356f;   // tile bounding-circle radius

    const float* gp = params + b * NG * 12;

    // ---- phase 1: cull (8 rounds x 128 threads) ----
    for (int k = 0; k < 8; ++k) {
        const int gi = k * TPB + tid;
        const float4 p0 = *(const float4*)(gp + gi * 12);      // px,py,e00,e01
        const float4 p1 = *(const float4*)(gp + gi * 12 + 4);  // e11,la,c0,c1
        const float rsq = gp[gi * 12 + 9];
        const float dx = cx - p0.x, dy = cy - p0.y;
        const float qd = -(p0.z * dx * dx + p0.w * dx * dy + p1.x * dy * dy);
        const float m  = sqrtf(fmaxf(qd, 0.f));     // ||d||_A
        const float u  = m - rt * rsq;
        const bool keep = (u <= 0.f) || (u * u <= TH_CULL + p1.y);
        const unsigned long long mask = __ballot(keep);
        int base = 0;
        if (lane == 0 && mask) base = atomicAdd(&scount, (int)__popcll(mask));
        base = __shfl(base, 0, 64);
        if (keep) {
            const int off = (int)__popcll(mask & ((1ull << lane) - 1ull));
            slist[base + off] = gi;
        }
    }
    __syncthreads();
    const int cnt = scount;

    // ---- phase 2: chunked LDS-staged splat ----
    const int px  = tid & 15, py = tid >> 4;       // py in 0..7
    const int X   = tx * 16 + px;
    const int Y0  = ty * 16 + py;
    const float xg  = -1.f + s2 * (float)X;
    const float yg0 = -1.f + s2 * (float)Y0;
    const float yg1 = -1.f + s2 * (float)(Y0 + 8);

    float r00 = 0.f, r01 = 0.f, r02 = 0.f, ws0 = 0.f;
    float r10 = 0.f, r11 = 0.f, r12 = 0.f, ws1 = 0.f;

    for (int cb = 0; cb < cnt; cb += CH) {
        const int n = min(CH, cnt - cb);
        __syncthreads();                 // previous chunk fully consumed
        if (tid < n) {
            const int gi = slist[cb + tid];
            const float4* src = (const float4*)(gp + gi * 12);
            const float4 a = src[0], bq = src[1], c = src[2];
            float4* d = (float4*)(sp + tid * 12);
            d[0] = a; d[1] = bq; d[2] = c;
        }
        __syncthreads();                 // chunk staged

        #pragma unroll 2
        for (int j = 0; j < n; ++j) {
            const float* p = sp + j * 12;
            const float4 P0 = *(const float4*)p;        // px,py,e00,e01
            const float4 P1 = *(const float4*)(p + 4);  // e11,la,c0,c1
            const float  c2 = p[8];

            const float dx = xg - P0.x;
            const float a1 = P0.z * dx;                 // e00*dx

            const float dy0 = yg0 - P0.y;
            const float q0  = fmaf(dx, fmaf(P0.w, dy0, a1),
                                   fmaf(P1.x * dy0, dy0, P1.y));
            const float w0  = EXP2(q0);
            ws0 += w0;
            r00 = fmaf(w0, P1.z, r00);
            r01 = fmaf(w0, P1.w, r01);
            r02 = fmaf(w0, c2,  r02);

            const float dy1 = yg1 - P0.y;
            const float q1  = fmaf(dx, fmaf(P0.w, dy1, a1),
                                   fmaf(P1.x * dy1, dy1, P1.y));
            const float w1  = EXP2(q1);
            ws1 += w1;
            r10 = fmaf(w1, P1.z, r10);
            r11 = fmaf(w1, P1.w, r11);
            r12 = fmaf(w1, c2,  r12);
        }
    }

    const float inv0 = 1.f / (ws0 + 1e-6f);
    const float inv1 = 1.f / (ws1 + 1e-6f);

    float* ob = out + (b * 3) * (HH * WW) + Y0 * WW + X;
    ob[0]                    = r00 * inv0;
    ob[HH * WW]              = r01 * inv0;
    ob[2 * HH * WW]          = r02 * inv0;
    ob[8 * WW]               = r10 * inv1;
    ob[HH * WW + 8 * WW]     = r11 * inv1;
    ob[2 * HH * WW + 8 * WW] = r12 * inv1;
}

extern "C" void kernel_launch(void* const* d_in, const int* in_sizes, int n_in,
                              void* d_out, int out_size, void* d_ws, size_t ws_size,
                              hipStream_t stream) {
    const float* feature = (const float*)d_in[0];   // (4,256,768) f32
    const float* proj_w  = (const float*)d_in[1];   // (36,768) f32
    const float* proj_b  = (const float*)d_in[2];   // (36,) f32
    float* params = (float*)d_ws;                   // 4096*12 f32 = 196 KB
    float* out    = (float*)d_out;                  // (4,3,256,256) f32

    param_kernel<<<NB * 256, 256, 0, stream>>>(feature, proj_w, proj_b, params);
    splat_kernel<<<NB * 256, TPB, 0, stream>>>(params, out);
}

// Round 9
// 95.110 us; speedup vs baseline: 2.5015x; 1.1688x over previous
//
#include <hip/hip_runtime.h>
#include <math.h>

#define HH 256
#define WW 256
#define NB 4
#define NG 1024      // gaussians per batch
#define DD 768
#define TH_CULL 42.0f   // cull if best-case weight exponent < -42 (err <= ~5e-4)
#define TPB 256         // splat threads per block (4 waves)
#define CH 128          // survivors staged to LDS per chunk

#if __has_builtin(__builtin_amdgcn_exp2f)
#define EXP2(x) __builtin_amdgcn_exp2f(x)
#else
#define EXP2(x) exp2f(x)
#endif

// params layout per gaussian: 12 floats (3x float4), 16B aligned:
//  [0]=px [1]=py [2]=e00 [3]=e01 [4]=e11 [5]=log2(alpha) [6]=c0 [7]=c1 [8]=c2
//  [9]=sqrt(-(e00+e11))  (>= sqrt(lambda_max) of positive form, for culling)
// weight = exp2(e00*dx^2 + e01*dx*dy + e11*dy^2 + log2(alpha)), e's < 0.

__global__ __launch_bounds__(256) void param_kernel(
    const float* __restrict__ feature, const float* __restrict__ proj_w,
    const float* __restrict__ proj_b, float* __restrict__ params)
{
    __shared__ float frow[DD];
    __shared__ float gsv[36];
    const int bt  = blockIdx.x;          // 0..1023
    const int tid = threadIdx.x;

    if (tid < DD / 4) {
        ((float4*)frow)[tid] = ((const float4*)(feature + bt * DD))[tid];
    }
    __syncthreads();

    const int wave = tid >> 6, lane = tid & 63;
    for (int i = 0; i < 9; ++i) {
        const int k = wave * 9 + i;
        const float* wrow = proj_w + k * DD;
        float s = 0.f;
        #pragma unroll
        for (int j = 0; j < DD / 64; ++j)
            s = fmaf(frow[lane + j * 64], wrow[lane + j * 64], s);
        #pragma unroll
        for (int off = 32; off; off >>= 1) s += __shfl_xor(s, off, 64);
        if (lane == 0) gsv[k] = s + proj_b[k];
    }
    __syncthreads();

    if (tid < 4) {
        const float* g = gsv + tid * 9;
        const float px = g[0], py = g[1];
        const float sx = expf(g[2]), sy = expf(g[3]);
        const float sx2 = sx * sx, sy2 = sy * sy;
        const float cs = cosf(g[4]), sn = sinf(g[4]);
        const float c00 = cs * cs * sx2 + sn * sn * sy2 + 1e-6f;
        const float c01 = cs * sn * (sx2 - sy2);
        const float c11 = sn * sn * sx2 + cs * cs * sy2 + 1e-6f;
        const float det = c00 * c11 - c01 * c01;
        const float i00 = c11 / det, i01 = -c01 / det, i11 = c00 / det;
        const float F = 0.72134752044448170368f;   // 0.5 * log2(e)
        const float e00 = -F * i00;
        const float e01 = -2.f * F * i01;
        const float e11 = -F * i11;
        const float la = -log2f(1.f + expf(-g[5]));   // log2(sigmoid)
        float* o = params + (bt * 4 + tid) * 12;
        o[0] = px;  o[1] = py;  o[2] = e00; o[3] = e01;
        o[4] = e11; o[5] = la;  o[6] = g[6]; o[7] = g[7];
        o[8] = g[8];
        o[9] = sqrtf(-(e00 + e11));
        o[10] = 0.f; o[11] = 0.f;
    }
}

// 1024 blocks x 256 threads (4 waves). Block = (tile, batch), batch-minor,
// tile index bit-reversed to scatter the hot center cluster across CUs/XCDs.
// Each WAVE covers the full 16x16 tile (thread = 2x2 px: (x,x+8)x(y,y+8));
// the 4 waves walk the culled survivor list stride-4 (each gaussian is
// LDS-read by exactly one wave). Partials combined via LDS at the end.
__global__ __launch_bounds__(TPB) void splat_kernel(
    const float* __restrict__ params, float* __restrict__ out)
{
    __shared__ int   slist[NG];        // 4 KB
    __shared__ float sp[CH * 12];      // 6 KB staged params
    __shared__ float red[48][64];      // 12 KB partial-sum combine
    __shared__ int   scount;

    const int blk  = blockIdx.x;
    const int tlin = blk >> 2;
    const int b    = blk & 3;                         // batch-minor
    const int tl   = (int)(__brev((unsigned)tlin) >> 24);   // scatter tiles
    const int ty   = tl >> 4, tx = tl & 15;
    const int tid  = threadIdx.x;
    const int lane = tid & 63;
    const int w4   = tid >> 6;                        // wave id 0..3

    if (tid == 0) scount = 0;
    __syncthreads();

    const float s2 = 2.f / 255.f;
    const float cx = -1.f + s2 * ((float)(tx * 16) + 7.5f);
    const float cy = -1.f + s2 * ((float)(ty * 16) + 7.5f);
    const float rt = s2 * 7.5f * 1.41421356f;   // tile bounding-circle radius

    const float* gp = params + b * NG * 12;

    // ---- phase 1: cull (4 rounds x 256 threads) ----
    for (int k = 0; k < 4; ++k) {
        const int gi = k * TPB + tid;
        const float4 p0 = *(const float4*)(gp + gi * 12);      // px,py,e00,e01
        const float4 p1 = *(const float4*)(gp + gi * 12 + 4);  // e11,la,c0,c1
        const float rsq = gp[gi * 12 + 9];
        const float dx = cx - p0.x, dy = cy - p0.y;
        const float qd = -(p0.z * dx * dx + p0.w * dx * dy + p1.x * dy * dy);
        const float m  = sqrtf(fmaxf(qd, 0.f));     // ||d||_A
        const float u  = m - rt * rsq;
        const bool keep = (u <= 0.f) || (u * u <= TH_CULL + p1.y);
        const unsigned long long mask = __ballot(keep);
        int base = 0;
        if (lane == 0 && mask) base = atomicAdd(&scount, (int)__popcll(mask));
        base = __shfl(base, 0, 64);
        if (keep) {
            const int off = (int)__popcll(mask & ((1ull << lane) - 1ull));
            slist[base + off] = gi;
        }
    }
    __syncthreads();
    const int cnt = scount;

    // ---- phase 2: chunked LDS-staged splat, 2x2 px per thread ----
    const int xl = lane & 7, yl = lane >> 3;
    const int X0 = tx * 16 + xl, Y0 = ty * 16 + yl;
    const float xg0 = -1.f + s2 * (float)X0;
    const float xg1 = -1.f + s2 * (float)(X0 + 8);
    const float yg0 = -1.f + s2 * (float)Y0;
    const float yg1 = -1.f + s2 * (float)(Y0 + 8);

    // acc[px][{r0,r1,r2,ws}], px: 0=(x0,y0) 1=(x1,y0) 2=(x0,y1) 3=(x1,y1)
    float a00=0.f,a01=0.f,a02=0.f,a03=0.f;
    float a10=0.f,a11=0.f,a12=0.f,a13=0.f;
    float a20=0.f,a21=0.f,a22=0.f,a23=0.f;
    float a30=0.f,a31=0.f,a32=0.f,a33=0.f;

    const int nch = (cnt + CH - 1) / CH;
    for (int c = 0; c < nch; ++c) {
        const int cb = c * CH;
        const int n  = min(CH, cnt - cb);
        __syncthreads();                 // previous chunk fully consumed
        for (int i = tid; i < n * 3; i += TPB) {
            const int gl = i / 3;
            const int wd = i - gl * 3;
            const int gi = slist[cb + gl];
            *(float4*)(sp + gl * 12 + wd * 4) =
                *(const float4*)(gp + gi * 12 + wd * 4);
        }
        __syncthreads();                 // chunk staged

        #pragma unroll 2
        for (int j = w4; j < n; j += 4) {
            const float* p = sp + j * 12;
            const float4 P0 = *(const float4*)p;        // px,py,e00,e01
            const float4 P1 = *(const float4*)(p + 4);  // e11,la,c0,c1
            const float  c2 = p[8];

            const float dx0 = xg0 - P0.x, dx1 = xg1 - P0.x;
            const float ax0 = P0.z * dx0, ax1 = P0.z * dx1;
            const float dy0 = yg0 - P0.y, dy1 = yg1 - P0.y;
            const float kd0 = P0.w * dy0, kd1 = P0.w * dy1;
            const float t20 = fmaf(P1.x * dy0, dy0, P1.y);
            const float t21 = fmaf(P1.x * dy1, dy1, P1.y);

            #define PXACC(R0,R1,R2,WS,DX,AX,KD,T2) { \
                const float q = fmaf(DX, (AX) + (KD), T2); \
                const float w = EXP2(q); \
                WS += w; \
                R0 = fmaf(w, P1.z, R0); \
                R1 = fmaf(w, P1.w, R1); \
                R2 = fmaf(w, c2,  R2); }
            PXACC(a00,a01,a02,a03, dx0,ax0,kd0,t20)
            PXACC(a10,a11,a12,a13, dx1,ax1,kd0,t20)
            PXACC(a20,a21,a22,a23, dx0,ax0,kd1,t21)
            PXACC(a30,a31,a32,a33, dx1,ax1,kd1,t21)
            #undef PXACC
        }
    }

    __syncthreads();
    if (w4 > 0) {
        const int rb = (w4 - 1) * 16;
        red[rb +  0][lane] = a00; red[rb +  1][lane] = a01;
        red[rb +  2][lane] = a02; red[rb +  3][lane] = a03;
        red[rb +  4][lane] = a10; red[rb +  5][lane] = a11;
        red[rb +  6][lane] = a12; red[rb +  7][lane] = a13;
        red[rb +  8][lane] = a20; red[rb +  9][lane] = a21;
        red[rb + 10][lane] = a22; red[rb + 11][lane] = a23;
        red[rb + 12][lane] = a30; red[rb + 13][lane] = a31;
        red[rb + 14][lane] = a32; red[rb + 15][lane] = a33;
    }
    __syncthreads();
    if (w4 == 0) {
        #pragma unroll
        for (int s = 0; s < 3; ++s) {
            const int rb = s * 16;
            a00 += red[rb +  0][lane]; a01 += red[rb +  1][lane];
            a02 += red[rb +  2][lane]; a03 += red[rb +  3][lane];
            a10 += red[rb +  4][lane]; a11 += red[rb +  5][lane];
            a12 += red[rb +  6][lane]; a13 += red[rb +  7][lane];
            a20 += red[rb +  8][lane]; a21 += red[rb +  9][lane];
            a22 += red[rb + 10][lane]; a23 += red[rb + 11][lane];
            a30 += red[rb + 12][lane]; a31 += red[rb + 13][lane];
            a32 += red[rb + 14][lane]; a33 += red[rb + 15][lane];
        }
        const float i0 = 1.f / (a03 + 1e-6f);
        const float i1 = 1.f / (a13 + 1e-6f);
        const float i2 = 1.f / (a23 + 1e-6f);
        const float i3 = 1.f / (a33 + 1e-6f);

        float* ob = out + (b * 3) * (HH * WW) + Y0 * WW + X0;
        // px0 (X0,Y0)
        ob[0]               = a00 * i0;
        ob[HH * WW]         = a01 * i0;
        ob[2 * HH * WW]     = a02 * i0;
        // px1 (X0+8,Y0)
        ob[8]               = a10 * i1;
        ob[HH * WW + 8]     = a11 * i1;
        ob[2 * HH * WW + 8] = a12 * i1;
        // px2 (X0,Y0+8)
        ob[8 * WW]               = a20 * i2;
        ob[HH * WW + 8 * WW]     = a21 * i2;
        ob[2 * HH * WW + 8 * WW] = a22 * i2;
        // px3 (X0+8,Y0+8)
        ob[8 * WW + 8]               = a30 * i3;
        ob[HH * WW + 8 * WW + 8]     = a31 * i3;
        ob[2 * HH * WW + 8 * WW + 8] = a32 * i3;
    }
}

extern "C" void kernel_launch(void* const* d_in, const int* in_sizes, int n_in,
                              void* d_out, int out_size, void* d_ws, size_t ws_size,
                              hipStream_t stream) {
    const float* feature = (const float*)d_in[0];   // (4,256,768) f32
    const float* proj_w  = (const float*)d_in[1];   // (36,768) f32
    const float* proj_b  = (const float*)d_in[2];   // (36,) f32
    float* params = (float*)d_ws;                   // 4096*12 f32 = 196 KB
    float* out    = (float*)d_out;                  // (4,3,256,256) f32

    param_kernel<<<NB * 256, 256, 0, stream>>>(feature, proj_w, proj_b, params);
    splat_kernel<<<NB * 256, TPB, 0, stream>>>(params, out);
}

// Round 13
// 94.406 us; speedup vs baseline: 2.5201x; 1.0075x over previous
//
#include <hip/hip_runtime.h>
#include <math.h>

#define HH 256
#define WW 256
#define NB 4
#define NG 1024      // gaussians per batch
#define DD 768
#define TH_CULL 42.0f   // cull if best-case weight exponent < -42 (err <= ~5e-4)
#define CH 64           // survivors staged to LDS per chunk (per quarter-list)

#if __has_builtin(__builtin_amdgcn_exp2f)
#define EXP2(x) __builtin_amdgcn_exp2f(x)
#else
#define EXP2(x) exp2f(x)
#endif

// d_ws layout (byte offsets):
//   params @ 0        : 4096 gaussians x 12 f32 (196 KB)
//   gcnt   @ 4  MB    : 1024 int   (per (b,tile) survivor count)
//   glist  @ 8  MB    : 1024x1024 int (per (b,tile) survivor indices)
//   accq   @ 16 MB    : [q][b][plane][65536] f32 = 16 MB (plane: r0,r1,r2,ws)

// params per gaussian: [0]=px [1]=py [2]=e00 [3]=e01 [4]=e11 [5]=log2(alpha)
//  [6..8]=c0..c2 [9]=sqrt(-(e00+e11)) [10..11]=pad
// weight = exp2(e00*dx^2 + e01*dx*dy + e11*dy^2 + log2(alpha)), e's < 0.

__global__ __launch_bounds__(256) void param_kernel(
    const float* __restrict__ feature, const float* __restrict__ proj_w,
    const float* __restrict__ proj_b, float* __restrict__ params)
{
    __shared__ float frow[DD];
    __shared__ float gsv[36];
    const int bt  = blockIdx.x;          // 0..1023
    const int tid = threadIdx.x;

    if (tid < DD / 4) {
        ((float4*)frow)[tid] = ((const float4*)(feature + bt * DD))[tid];
    }
    __syncthreads();

    const int wave = tid >> 6, lane = tid & 63;
    for (int i = 0; i < 9; ++i) {
        const int k = wave * 9 + i;
        const float* wrow = proj_w + k * DD;
        float s = 0.f;
        #pragma unroll
        for (int j = 0; j < DD / 64; ++j)
            s = fmaf(frow[lane + j * 64], wrow[lane + j * 64], s);
        #pragma unroll
        for (int off = 32; off; off >>= 1) s += __shfl_xor(s, off, 64);
        if (lane == 0) gsv[k] = s + proj_b[k];
    }
    __syncthreads();

    if (tid < 4) {
        const float* g = gsv + tid * 9;
        const float px = g[0], py = g[1];
        const float sx = expf(g[2]), sy = expf(g[3]);
        const float sx2 = sx * sx, sy2 = sy * sy;
        const float cs = cosf(g[4]), sn = sinf(g[4]);
        const float c00 = cs * cs * sx2 + sn * sn * sy2 + 1e-6f;
        const float c01 = cs * sn * (sx2 - sy2);
        const float c11 = sn * sn * sx2 + cs * cs * sy2 + 1e-6f;
        const float det = c00 * c11 - c01 * c01;
        const float i00 = c11 / det, i01 = -c01 / det, i11 = c00 / det;
        const float F = 0.72134752044448170368f;   // 0.5 * log2(e)
        const float e00 = -F * i00;
        const float e01 = -2.f * F * i01;
        const float e11 = -F * i11;
        const float la = -log2f(1.f + expf(-g[5]));   // log2(sigmoid)
        float* o = params + (bt * 4 + tid) * 12;
        o[0] = px;  o[1] = py;  o[2] = e00; o[3] = e01;
        o[4] = e11; o[5] = la;  o[6] = g[6]; o[7] = g[7];
        o[8] = g[8];
        o[9] = sqrtf(-(e00 + e11));
        o[10] = 0.f; o[11] = 0.f;
    }
}

// 1024 blocks (b*256+tile) x 256 thr: cull + compact survivor indices to global.
__global__ __launch_bounds__(256) void cull_kernel(
    const float* __restrict__ params, int* __restrict__ gcnt,
    int* __restrict__ glist)
{
    __shared__ int scount;
    const int blk = blockIdx.x;
    const int b   = blk >> 8;
    const int tl  = blk & 255;
    const int ty  = tl >> 4, tx = tl & 15;
    const int tid = threadIdx.x;
    const int lane = tid & 63;

    if (tid == 0) scount = 0;
    __syncthreads();

    const float s2 = 2.f / 255.f;
    const float cx = -1.f + s2 * ((float)(tx * 16) + 7.5f);
    const float cy = -1.f + s2 * ((float)(ty * 16) + 7.5f);
    const float rt = s2 * 7.5f * 1.41421356f;   // tile bounding-circle radius

    const float* gp = params + b * NG * 12;
    int* lst = glist + blk * NG;

    for (int k = 0; k < 4; ++k) {
        const int gi = k * 256 + tid;
        const float4 p0 = *(const float4*)(gp + gi * 12);      // px,py,e00,e01
        const float4 p1 = *(const float4*)(gp + gi * 12 + 4);  // e11,la,c0,c1
        const float rsq = gp[gi * 12 + 9];
        const float dx = cx - p0.x, dy = cy - p0.y;
        const float qd = -(p0.z * dx * dx + p0.w * dx * dy + p1.x * dy * dy);
        const float m  = sqrtf(fmaxf(qd, 0.f));     // ||d||_A
        const float u  = m - rt * rsq;
        const bool keep = (u <= 0.f) || (u * u <= TH_CULL + p1.y);
        const unsigned long long mask = __ballot(keep);
        int base = 0;
        if (lane == 0 && mask) base = atomicAdd(&scount, (int)__popcll(mask));
        base = __shfl(base, 0, 64);
        if (keep) {
            const int off = (int)__popcll(mask & ((1ull << lane) - 1ull));
            lst[base + off] = gi;
        }
    }
    __syncthreads();
    if (tid == 0) gcnt[blk] = scount;
}

// 4096 blocks x 256 thr (4 waves). blk -> {q=blk&3, b=(blk>>2)&3, tile=blk>>4}.
// Each (b,tile) has 4 quarter-blocks; quarter q walks survivor indices
// {i : i mod 4 == q}; within the block the 4 waves stride that sublist by 4
// -> a hot tile's list is split across 16 waves. Each WAVE covers the whole
// 16x16 tile (lane = 2x2 px). Partials: waves reduce via LDS to wave0, which
// stores to the block's private q-plane (no atomics, deterministic, disjoint).
__global__ __launch_bounds__(256) void splat_kernel(
    const float* __restrict__ params, const int* __restrict__ gcnt,
    const int* __restrict__ glist, float* __restrict__ accq)
{
    __shared__ float sp[CH * 12];      // 3 KB staged params
    __shared__ float red[48][64];      // 12 KB partial-sum combine

    const int blk  = blockIdx.x;
    const int q    = blk & 3;
    const int b    = (blk >> 2) & 3;
    const int tl   = blk >> 4;                        // 0..255
    const int ty   = tl >> 4, tx = tl & 15;
    const int tid  = threadIdx.x;
    const int lane = tid & 63;
    const int w4   = tid >> 6;                        // wave id 0..3

    const int bt  = b * 256 + tl;
    const int cnt = gcnt[bt];
    const int K   = (cnt - q + 3) >> 2;               // #indices == q (mod 4)
    const int* lst = glist + bt * NG;
    const float* gp = params + b * NG * 12;

    const float s2 = 2.f / 255.f;
    const int xl = lane & 7, yl = lane >> 3;
    const int X0 = tx * 16 + xl, Y0 = ty * 16 + yl;
    const float xg0 = -1.f + s2 * (float)X0;
    const float xg1 = -1.f + s2 * (float)(X0 + 8);
    const float yg0 = -1.f + s2 * (float)Y0;
    const float yg1 = -1.f + s2 * (float)(Y0 + 8);

    float a00=0.f,a01=0.f,a02=0.f,a03=0.f;
    float a10=0.f,a11=0.f,a12=0.f,a13=0.f;
    float a20=0.f,a21=0.f,a22=0.f,a23=0.f;
    float a30=0.f,a31=0.f,a32=0.f,a33=0.f;

    for (int cb = 0; cb < K; cb += CH) {
        const int n = min(CH, K - cb);
        __syncthreads();                 // previous chunk fully consumed
        for (int i = tid; i < n * 3; i += 256) {
            const int gl = i / 3;
            const int wd = i - gl * 3;
            const int gi = lst[(cb + gl) * 4 + q];
            *(float4*)(sp + gl * 12 + wd * 4) =
                *(const float4*)(gp + gi * 12 + wd * 4);
        }
        __syncthreads();                 // chunk staged

        #pragma unroll 2
        for (int j = w4; j < n; j += 4) {
            const float* p = sp + j * 12;
            const float4 P0 = *(const float4*)p;        // px,py,e00,e01
            const float4 P1 = *(const float4*)(p + 4);  // e11,la,c0,c1
            const float  c2 = p[8];

            const float dx0 = xg0 - P0.x, dx1 = xg1 - P0.x;
            const float ax0 = P0.z * dx0, ax1 = P0.z * dx1;
            const float dy0 = yg0 - P0.y, dy1 = yg1 - P0.y;
            const float kd0 = P0.w * dy0, kd1 = P0.w * dy1;
            const float t20 = fmaf(P1.x * dy0, dy0, P1.y);
            const float t21 = fmaf(P1.x * dy1, dy1, P1.y);

            #define PXACC(R0,R1,R2,WS,DX,AX,KD,T2) { \
                const float qq = fmaf(DX, (AX) + (KD), T2); \
                const float w = EXP2(qq); \
                WS += w; \
                R0 = fmaf(w, P1.z, R0); \
                R1 = fmaf(w, P1.w, R1); \
                R2 = fmaf(w, c2,  R2); }
            PXACC(a00,a01,a02,a03, dx0,ax0,kd0,t20)
            PXACC(a10,a11,a12,a13, dx1,ax1,kd0,t20)
            PXACC(a20,a21,a22,a23, dx0,ax0,kd1,t21)
            PXACC(a30,a31,a32,a33, dx1,ax1,kd1,t21)
            #undef PXACC
        }
    }

    __syncthreads();
    if (w4 > 0) {
        const int rb = (w4 - 1) * 16;
        red[rb +  0][lane] = a00; red[rb +  1][lane] = a01;
        red[rb +  2][lane] = a02; red[rb +  3][lane] = a03;
        red[rb +  4][lane] = a10; red[rb +  5][lane] = a11;
        red[rb +  6][lane] = a12; red[rb +  7][lane] = a13;
        red[rb +  8][lane] = a20; red[rb +  9][lane] = a21;
        red[rb + 10][lane] = a22; red[rb + 11][lane] = a23;
        red[rb + 12][lane] = a30; red[rb + 13][lane] = a31;
        red[rb + 14][lane] = a32; red[rb + 15][lane] = a33;
    }
    __syncthreads();
    if (w4 == 0) {
        #pragma unroll
        for (int s = 0; s < 3; ++s) {
            const int rb = s * 16;
            a00 += red[rb +  0][lane]; a01 += red[rb +  1][lane];
            a02 += red[rb +  2][lane]; a03 += red[rb +  3][lane];
            a10 += red[rb +  4][lane]; a11 += red[rb +  5][lane];
            a12 += red[rb +  6][lane]; a13 += red[rb +  7][lane];
            a20 += red[rb +  8][lane]; a21 += red[rb +  9][lane];
            a22 += red[rb + 10][lane]; a23 += red[rb + 11][lane];
            a30 += red[rb + 12][lane]; a31 += red[rb + 13][lane];
            a32 += red[rb + 14][lane]; a33 += red[rb + 15][lane];
        }
        // store to this block's private q-plane: accq[q][b][plane][256*256]
        float* ap = accq + (size_t)((q * 4 + b) * 4) * (HH * WW)
                        + Y0 * WW + X0;
        const int PL = HH * WW;
        ap[0]                = a00; ap[8]                = a10;
        ap[8 * WW]           = a20; ap[8 * WW + 8]       = a30;
        ap[PL]               = a01; ap[PL + 8]           = a11;
        ap[PL + 8 * WW]      = a21; ap[PL + 8 * WW + 8]  = a31;
        ap[2*PL]             = a02; ap[2*PL + 8]         = a12;
        ap[2*PL + 8 * WW]    = a22; ap[2*PL + 8 * WW + 8]= a32;
        ap[3*PL]             = a03; ap[3*PL + 8]         = a13;
        ap[3*PL + 8 * WW]    = a23; ap[3*PL + 8 * WW + 8]= a33;
    }
}

// 256 blocks x 256 thr, thread = 4 px (float4): sum 4 q-planes, divide.
__global__ __launch_bounds__(256) void normalize_kernel(
    const float* __restrict__ accq, float* __restrict__ out)
{
    const int blk = blockIdx.x;
    const int b   = blk >> 6, seg = blk & 63;
    const int px  = seg * 1024 + threadIdx.x * 4;
    const int PL  = HH * WW;

    float4 r0, r1, r2, ws;
    {
        const float* base = accq + (size_t)((0 * 4 + b) * 4) * PL + px;
        r0 = *(const float4*)(base);
        r1 = *(const float4*)(base + PL);
        r2 = *(const float4*)(base + 2 * PL);
        ws = *(const float4*)(base + 3 * PL);
    }
    #pragma unroll
    for (int q = 1; q < 4; ++q) {
        const float* base = accq + (size_t)((q * 4 + b) * 4) * PL + px;
        const float4 t0 = *(const float4*)(base);
        const float4 t1 = *(const float4*)(base + PL);
        const float4 t2 = *(const float4*)(base + 2 * PL);
        const float4 t3 = *(const float4*)(base + 3 * PL);
        r0.x += t0.x; r0.y += t0.y; r0.z += t0.z; r0.w += t0.w;
        r1.x += t1.x; r1.y += t1.y; r1.z += t1.z; r1.w += t1.w;
        r2.x += t2.x; r2.y += t2.y; r2.z += t2.z; r2.w += t2.w;
        ws.x += t3.x; ws.y += t3.y; ws.z += t3.z; ws.w += t3.w;
    }
    float4 inv;
    inv.x = 1.f / (ws.x + 1e-6f); inv.y = 1.f / (ws.y + 1e-6f);
    inv.z = 1.f / (ws.z + 1e-6f); inv.w = 1.f / (ws.w + 1e-6f);

    float* ob = out + (size_t)(b * 3) * PL + px;
    float4 o0, o1, o2;
    o0.x = r0.x * inv.x; o0.y = r0.y * inv.y; o0.z = r0.z * inv.z; o0.w = r0.w * inv.w;
    o1.x = r1.x * inv.x; o1.y = r1.y * inv.y; o1.z = r1.z * inv.z; o1.w = r1.w * inv.w;
    o2.x = r2.x * inv.x; o2.y = r2.y * inv.y; o2.z = r2.z * inv.z; o2.w = r2.w * inv.w;
    *(float4*)(ob)          = o0;
    *(float4*)(ob + PL)     = o1;
    *(float4*)(ob + 2 * PL) = o2;
}

extern "C" void kernel_launch(void* const* d_in, const int* in_sizes, int n_in,
                              void* d_out, int out_size, void* d_ws, size_t ws_size,
                              hipStream_t stream) {
    const float* feature = (const float*)d_in[0];   // (4,256,768) f32
    const float* proj_w  = (const float*)d_in[1];   // (36,768) f32
    const float* proj_b  = (const float*)d_in[2];   // (36,) f32
    float* out    = (float*)d_out;                  // (4,3,256,256) f32

    float* params = (float*)d_ws;
    int*   gcnt   = (int*)((char*)d_ws + (4u << 20));
    int*   glist  = (int*)((char*)d_ws + (8u << 20));
    float* accq   = (float*)((char*)d_ws + (16u << 20));

    hipMemsetAsync(accq, 0, 16u << 20, stream);     // zero quarter-planes
    param_kernel<<<NB * 256, 256, 0, stream>>>(feature, proj_w, proj_b, params);
    cull_kernel<<<NB * 256, 256, 0, stream>>>(params, gcnt, glist);
    splat_kernel<<<NB * 256 * 4, 256, 0, stream>>>(params, gcnt, glist, accq);
    normalize_kernel<<<256, 256, 0, stream>>>(accq, out);
}

// Round 14
// 94.006 us; speedup vs baseline: 2.5309x; 1.0043x over previous
//
#include <hip/hip_runtime.h>
#include <math.h>

#define HH 256
#define WW 256
#define NB 4
#define NG 1024      // gaussians per batch
#define DD 768
#define TH_CULL 42.0f   // cull if best-case weight exponent < -42 (err <= ~5e-4)
#define TPB 256         // splat threads per block (4 waves)
#define CH 256          // survivors staged to LDS per chunk (12 KB)

#if __has_builtin(__builtin_amdgcn_exp2f)
#define EXP2(x) __builtin_amdgcn_exp2f(x)
#else
#define EXP2(x) exp2f(x)
#endif

// params per gaussian (12 floats, 16B aligned):
//  [0]=px [1]=py [2]=e00 [3]=e01 [4]=e11 [5]=log2(alpha) [6..8]=c0..c2
//  [9]=sqrt(-(e00+e11)) [10..11]=pad
// weight = exp2(e00*dx^2 + e01*dx*dy + e11*dy^2 + log2(alpha)), e's < 0.

__global__ __launch_bounds__(256) void param_kernel(
    const float* __restrict__ feature, const float* __restrict__ proj_w,
    const float* __restrict__ proj_b, float* __restrict__ params)
{
    __shared__ float frow[DD];
    __shared__ float gsv[36];
    const int bt  = blockIdx.x;          // 0..1023
    const int tid = threadIdx.x;

    if (tid < DD / 4) {
        ((float4*)frow)[tid] = ((const float4*)(feature + bt * DD))[tid];
    }
    __syncthreads();

    const int wave = tid >> 6, lane = tid & 63;
    for (int i = 0; i < 9; ++i) {
        const int k = wave * 9 + i;
        const float* wrow = proj_w + k * DD;
        float s = 0.f;
        #pragma unroll
        for (int j = 0; j < DD / 64; ++j)
            s = fmaf(frow[lane + j * 64], wrow[lane + j * 64], s);
        #pragma unroll
        for (int off = 32; off; off >>= 1) s += __shfl_xor(s, off, 64);
        if (lane == 0) gsv[k] = s + proj_b[k];
    }
    __syncthreads();

    if (tid < 4) {
        const float* g = gsv + tid * 9;
        const float px = g[0], py = g[1];
        const float sx = expf(g[2]), sy = expf(g[3]);
        const float sx2 = sx * sx, sy2 = sy * sy;
        const float cs = cosf(g[4]), sn = sinf(g[4]);
        const float c00 = cs * cs * sx2 + sn * sn * sy2 + 1e-6f;
        const float c01 = cs * sn * (sx2 - sy2);
        const float c11 = sn * sn * sx2 + cs * cs * sy2 + 1e-6f;
        const float det = c00 * c11 - c01 * c01;
        const float i00 = c11 / det, i01 = -c01 / det, i11 = c00 / det;
        const float F = 0.72134752044448170368f;   // 0.5 * log2(e)
        const float e00 = -F * i00;
        const float e01 = -2.f * F * i01;
        const float e11 = -F * i11;
        const float la = -log2f(1.f + expf(-g[5]));   // log2(sigmoid)
        float* o = params + (bt * 4 + tid) * 12;
        o[0] = px;  o[1] = py;  o[2] = e00; o[3] = e01;
        o[4] = e11; o[5] = la;  o[6] = g[6]; o[7] = g[7];
        o[8] = g[8];
        o[9] = sqrtf(-(e00 + e11));
        o[10] = 0.f; o[11] = 0.f;
    }
}

// 1024 blocks x 256 thr (4 waves). blk -> {b = blk&3 (batch-minor),
// tile = brev8(blk>>2)} to scatter the hot center cluster across CUs.
// Phase 1: in-block cull+compact into LDS slist (ballot/popc).
// Phase 2: chunks of 256 survivors staged to LDS once (1 barrier pair per
//          chunk); each WAVE covers the whole 16x16 tile (lane = 2x2 px) and
//          walks the chunk stride-4 -> hot tile split across 4 SIMDs with
//          <=64 uninterrupted iterations per wave per chunk.
// Phase 3: LDS reduce to wave0, divide by weight-sum, write out directly.
__global__ __launch_bounds__(TPB) void splat_kernel(
    const float* __restrict__ params, float* __restrict__ out)
{
    __shared__ int   slist[NG];        // 4 KB
    __shared__ float sp[CH * 12];      // 12 KB staged params
    __shared__ float red[48][64];      // 12 KB partial-sum combine
    __shared__ int   scount;

    const int blk  = blockIdx.x;
    const int tlin = blk >> 2;
    const int b    = blk & 3;                               // batch-minor
    const int tl   = (int)(__brev((unsigned)tlin) >> 24);   // scatter tiles
    const int ty   = tl >> 4, tx = tl & 15;
    const int tid  = threadIdx.x;
    const int lane = tid & 63;
    const int w4   = tid >> 6;                              // wave id 0..3

    if (tid == 0) scount = 0;
    __syncthreads();

    const float s2 = 2.f / 255.f;
    const float cx = -1.f + s2 * ((float)(tx * 16) + 7.5f);
    const float cy = -1.f + s2 * ((float)(ty * 16) + 7.5f);
    const float rt = s2 * 7.5f * 1.41421356f;   // tile bounding-circle radius

    const float* gp = params + b * NG * 12;

    // ---- phase 1: cull (4 rounds x 256 threads) ----
    for (int k = 0; k < 4; ++k) {
        const int gi = k * 256 + tid;
        const float4 p0 = *(const float4*)(gp + gi * 12);      // px,py,e00,e01
        const float4 p1 = *(const float4*)(gp + gi * 12 + 4);  // e11,la,c0,c1
        const float rsq = gp[gi * 12 + 9];
        const float dx = cx - p0.x, dy = cy - p0.y;
        const float qd = -(p0.z * dx * dx + p0.w * dx * dy + p1.x * dy * dy);
        const float m  = sqrtf(fmaxf(qd, 0.f));     // ||d||_A
        const float u  = m - rt * rsq;
        const bool keep = (u <= 0.f) || (u * u <= TH_CULL + p1.y);
        const unsigned long long mask = __ballot(keep);
        int base = 0;
        if (lane == 0 && mask) base = atomicAdd(&scount, (int)__popcll(mask));
        base = __shfl(base, 0, 64);
        if (keep) {
            const int off = (int)__popcll(mask & ((1ull << lane) - 1ull));
            slist[base + off] = gi;
        }
    }
    __syncthreads();
    const int cnt = scount;

    // ---- phase 2: chunked splat (2x2 px per lane, waves stride 4) ----
    const int xl = lane & 7, yl = lane >> 3;
    const int X0 = tx * 16 + xl, Y0 = ty * 16 + yl;
    const float xg0 = -1.f + s2 * (float)X0;
    const float xg1 = -1.f + s2 * (float)(X0 + 8);
    const float yg0 = -1.f + s2 * (float)Y0;
    const float yg1 = -1.f + s2 * (float)(Y0 + 8);

    float a00=0.f,a01=0.f,a02=0.f,a03=0.f;
    float a10=0.f,a11=0.f,a12=0.f,a13=0.f;
    float a20=0.f,a21=0.f,a22=0.f,a23=0.f;
    float a30=0.f,a31=0.f,a32=0.f,a33=0.f;

    for (int cb = 0; cb < cnt; cb += CH) {
        const int n = min(CH, cnt - cb);
        __syncthreads();                 // previous chunk fully consumed
        for (int i = tid; i < n * 3; i += TPB) {
            const int gl = i / 3;
            const int wd = i - gl * 3;
            const int gi = slist[cb + gl];
            *(float4*)(sp + gl * 12 + wd * 4) =
                *(const float4*)(gp + gi * 12 + wd * 4);
        }
        __syncthreads();                 // chunk staged

        #pragma unroll 2
        for (int j = w4; j < n; j += 4) {
            const float* p = sp + j * 12;
            const float4 P0 = *(const float4*)p;        // px,py,e00,e01
            const float4 P1 = *(const float4*)(p + 4);  // e11,la,c0,c1
            const float  c2 = p[8];

            const float dx0 = xg0 - P0.x, dx1 = xg1 - P0.x;
            const float ax0 = P0.z * dx0, ax1 = P0.z * dx1;
            const float dy0 = yg0 - P0.y, dy1 = yg1 - P0.y;
            const float kd0 = P0.w * dy0, kd1 = P0.w * dy1;
            const float t20 = fmaf(P1.x * dy0, dy0, P1.y);
            const float t21 = fmaf(P1.x * dy1, dy1, P1.y);

            #define PXACC(R0,R1,R2,WS,DX,AX,KD,T2) { \
                const float qq = fmaf(DX, (AX) + (KD), T2); \
                const float w = EXP2(qq); \
                WS += w; \
                R0 = fmaf(w, P1.z, R0); \
                R1 = fmaf(w, P1.w, R1); \
                R2 = fmaf(w, c2,  R2); }
            PXACC(a00,a01,a02,a03, dx0,ax0,kd0,t20)
            PXACC(a10,a11,a12,a13, dx1,ax1,kd0,t20)
            PXACC(a20,a21,a22,a23, dx0,ax0,kd1,t21)
            PXACC(a30,a31,a32,a33, dx1,ax1,kd1,t21)
            #undef PXACC
        }
    }

    // ---- phase 3: combine partials, normalize, write out ----
    __syncthreads();
    if (w4 > 0) {
        const int rb = (w4 - 1) * 16;
        red[rb +  0][lane] = a00; red[rb +  1][lane] = a01;
        red[rb +  2][lane] = a02; red[rb +  3][lane] = a03;
        red[rb +  4][lane] = a10; red[rb +  5][lane] = a11;
        red[rb +  6][lane] = a12; red[rb +  7][lane] = a13;
        red[rb +  8][lane] = a20; red[rb +  9][lane] = a21;
        red[rb + 10][lane] = a22; red[rb + 11][lane] = a23;
        red[rb + 12][lane] = a30; red[rb + 13][lane] = a31;
        red[rb + 14][lane] = a32; red[rb + 15][lane] = a33;
    }
    __syncthreads();
    if (w4 == 0) {
        #pragma unroll
        for (int s = 0; s < 3; ++s) {
            const int rb = s * 16;
            a00 += red[rb +  0][lane]; a01 += red[rb +  1][lane];
            a02 += red[rb +  2][lane]; a03 += red[rb +  3][lane];
            a10 += red[rb +  4][lane]; a11 += red[rb +  5][lane];
            a12 += red[rb +  6][lane]; a13 += red[rb +  7][lane];
            a20 += red[rb +  8][lane]; a21 += red[rb +  9][lane];
            a22 += red[rb + 10][lane]; a23 += red[rb + 11][lane];
            a30 += red[rb + 12][lane]; a31 += red[rb + 13][lane];
            a32 += red[rb + 14][lane]; a33 += red[rb + 15][lane];
        }
        const float i0 = 1.f / (a03 + 1e-6f);
        const float i1 = 1.f / (a13 + 1e-6f);
        const float i2 = 1.f / (a23 + 1e-6f);
        const float i3 = 1.f / (a33 + 1e-6f);

        const int PL = HH * WW;
        float* ob = out + (b * 3) * PL + Y0 * WW + X0;
        ob[0]                    = a00 * i0;
        ob[PL]                   = a01 * i0;
        ob[2 * PL]               = a02 * i0;
        ob[8]                    = a10 * i1;
        ob[PL + 8]               = a11 * i1;
        ob[2 * PL + 8]           = a12 * i1;
        ob[8 * WW]               = a20 * i2;
        ob[PL + 8 * WW]          = a21 * i2;
        ob[2 * PL + 8 * WW]      = a22 * i2;
        ob[8 * WW + 8]           = a30 * i3;
        ob[PL + 8 * WW + 8]      = a31 * i3;
        ob[2 * PL + 8 * WW + 8]  = a32 * i3;
    }
}

extern "C" void kernel_launch(void* const* d_in, const int* in_sizes, int n_in,
                              void* d_out, int out_size, void* d_ws, size_t ws_size,
                              hipStream_t stream) {
    const float* feature = (const float*)d_in[0];   // (4,256,768) f32
    const float* proj_w  = (const float*)d_in[1];   // (36,768) f32
    const float* proj_b  = (const float*)d_in[2];   // (36,) f32
    float* params = (float*)d_ws;                   // 4096*12 f32 = 196 KB
    float* out    = (float*)d_out;                  // (4,3,256,256) f32

    param_kernel<<<NB * 256, 256, 0, stream>>>(feature, proj_w, proj_b, params);
    splat_kernel<<<NB * 256, TPB, 0, stream>>>(params, out);
}

// Round 15
// 92.931 us; speedup vs baseline: 2.5601x; 1.0116x over previous
//
#include <hip/hip_runtime.h>
#include <math.h>

#define HH 256
#define WW 256
#define NB 4
#define NG 1024      // gaussians per batch
#define DD 768
#define TH_CULL 36.0f   // cull if best-case weight exponent < -36 (err ~1e-4)
#define TPB 256         // splat threads per block (4 waves)
#define CH 256          // survivors staged to LDS per chunk (12 KB)

#if __has_builtin(__builtin_amdgcn_exp2f)
#define EXP2(x) __builtin_amdgcn_exp2f(x)
#else
#define EXP2(x) exp2f(x)
#endif

// params per gaussian (12 floats, 16B aligned):
//  [0]=px [1]=py [2]=e00 [3]=e01 [4]=e11 [5]=log2(alpha) [6..8]=c0..c2
//  [9]=sqrt(-(e00+e11)) [10..11]=pad
// weight = exp2(e00*dx^2 + e01*dx*dy + e11*dy^2 + log2(alpha)), e's < 0.

__global__ __launch_bounds__(256) void param_kernel(
    const float* __restrict__ feature, const float* __restrict__ proj_w,
    const float* __restrict__ proj_b, float* __restrict__ params)
{
    __shared__ float frow[DD];
    __shared__ float gsv[36];
    const int bt  = blockIdx.x;          // 0..1023
    const int tid = threadIdx.x;

    if (tid < DD / 4) {
        ((float4*)frow)[tid] = ((const float4*)(feature + bt * DD))[tid];
    }
    __syncthreads();

    const int wave = tid >> 6, lane = tid & 63;
    for (int i = 0; i < 9; ++i) {
        const int k = wave * 9 + i;
        const float* wrow = proj_w + k * DD;
        float s = 0.f;
        #pragma unroll
        for (int j = 0; j < DD / 64; ++j)
            s = fmaf(frow[lane + j * 64], wrow[lane + j * 64], s);
        #pragma unroll
        for (int off = 32; off; off >>= 1) s += __shfl_xor(s, off, 64);
        if (lane == 0) gsv[k] = s + proj_b[k];
    }
    __syncthreads();

    if (tid < 4) {
        const float* g = gsv + tid * 9;
        const float px = g[0], py = g[1];
        const float sx = expf(g[2]), sy = expf(g[3]);
        const float sx2 = sx * sx, sy2 = sy * sy;
        const float cs = cosf(g[4]), sn = sinf(g[4]);
        const float c00 = cs * cs * sx2 + sn * sn * sy2 + 1e-6f;
        const float c01 = cs * sn * (sx2 - sy2);
        const float c11 = sn * sn * sx2 + cs * cs * sy2 + 1e-6f;
        const float det = c00 * c11 - c01 * c01;
        const float i00 = c11 / det, i01 = -c01 / det, i11 = c00 / det;
        const float F = 0.72134752044448170368f;   // 0.5 * log2(e)
        const float e00 = -F * i00;
        const float e01 = -2.f * F * i01;
        const float e11 = -F * i11;
        const float la = -log2f(1.f + expf(-g[5]));   // log2(sigmoid)
        float* o = params + (bt * 4 + tid) * 12;
        o[0] = px;  o[1] = py;  o[2] = e00; o[3] = e01;
        o[4] = e11; o[5] = la;  o[6] = g[6]; o[7] = g[7];
        o[8] = g[8];
        o[9] = sqrtf(-(e00 + e11));
        o[10] = 0.f; o[11] = 0.f;
    }
}

// 1024 blocks x 256 thr (4 waves). blk -> {b = blk&3 (batch-minor),
// tile = brev8(blk>>2)} to scatter the hot center cluster across CUs.
// Phase 1: in-block cull+compact into LDS slist (ballot/popc).
// Phase 2: chunks of 256 survivors staged to LDS; each WAVE covers the whole
//          16x16 tile (lane = 2x2 px) walking the chunk stride-4, with an
//          explicit 2-deep software pipeline: gaussian j+4's params are
//          register-loaded before computing gaussian j (breaks the
//          ds_read -> fma -> exp dependent-latency chain).
// Phase 3: LDS reduce to wave0, divide by weight-sum, write out directly.
__global__ __launch_bounds__(TPB) void splat_kernel(
    const float* __restrict__ params, float* __restrict__ out)
{
    __shared__ int   slist[NG];          // 4 KB
    __shared__ float sp[CH * 12 + 48];   // 12 KB staged params (+pad for prefetch over-read)
    __shared__ float red[48][64];        // 12 KB partial-sum combine
    __shared__ int   scount;

    const int blk  = blockIdx.x;
    const int tlin = blk >> 2;
    const int b    = blk & 3;                               // batch-minor
    const int tl   = (int)(__brev((unsigned)tlin) >> 24);   // scatter tiles
    const int ty   = tl >> 4, tx = tl & 15;
    const int tid  = threadIdx.x;
    const int lane = tid & 63;
    const int w4   = tid >> 6;                              // wave id 0..3

    if (tid == 0) scount = 0;
    __syncthreads();

    const float s2 = 2.f / 255.f;
    const float cx = -1.f + s2 * ((float)(tx * 16) + 7.5f);
    const float cy = -1.f + s2 * ((float)(ty * 16) + 7.5f);
    const float rt = s2 * 7.5f * 1.41421356f;   // tile bounding-circle radius

    const float* gp = params + b * NG * 12;

    // ---- phase 1: cull (4 rounds x 256 threads) ----
    for (int k = 0; k < 4; ++k) {
        const int gi = k * 256 + tid;
        const float4 p0 = *(const float4*)(gp + gi * 12);      // px,py,e00,e01
        const float4 p1 = *(const float4*)(gp + gi * 12 + 4);  // e11,la,c0,c1
        const float rsq = gp[gi * 12 + 9];
        const float dx = cx - p0.x, dy = cy - p0.y;
        const float qd = -(p0.z * dx * dx + p0.w * dx * dy + p1.x * dy * dy);
        const float m  = sqrtf(fmaxf(qd, 0.f));     // ||d||_A
        const float u  = m - rt * rsq;
        const bool keep = (u <= 0.f) || (u * u <= TH_CULL + p1.y);
        const unsigned long long mask = __ballot(keep);
        int base = 0;
        if (lane == 0 && mask) base = atomicAdd(&scount, (int)__popcll(mask));
        base = __shfl(base, 0, 64);
        if (keep) {
            const int off = (int)__popcll(mask & ((1ull << lane) - 1ull));
            slist[base + off] = gi;
        }
    }
    __syncthreads();
    const int cnt = scount;

    // ---- phase 2: chunked splat (2x2 px per lane, waves stride 4) ----
    const int xl = lane & 7, yl = lane >> 3;
    const int X0 = tx * 16 + xl, Y0 = ty * 16 + yl;
    const float xg0 = -1.f + s2 * (float)X0;
    const float xg1 = -1.f + s2 * (float)(X0 + 8);
    const float yg0 = -1.f + s2 * (float)Y0;
    const float yg1 = -1.f + s2 * (float)(Y0 + 8);

    float a00=0.f,a01=0.f,a02=0.f,a03=0.f;
    float a10=0.f,a11=0.f,a12=0.f,a13=0.f;
    float a20=0.f,a21=0.f,a22=0.f,a23=0.f;
    float a30=0.f,a31=0.f,a32=0.f,a33=0.f;

    for (int cb = 0; cb < cnt; cb += CH) {
        const int n = min(CH, cnt - cb);
        __syncthreads();                 // previous chunk fully consumed
        for (int i = tid; i < n * 3; i += TPB) {
            const int gl = i / 3;
            const int wd = i - gl * 3;
            const int gi = slist[cb + gl];
            *(float4*)(sp + gl * 12 + wd * 4) =
                *(const float4*)(gp + gi * 12 + wd * 4);
        }
        __syncthreads();                 // chunk staged

        // 2-deep software pipeline: prefetch j+4 while computing j.
        int j = w4;
        float4 P0, P1; float c2v;
        if (j < n) {
            P0  = *(const float4*)(sp + j * 12);
            P1  = *(const float4*)(sp + j * 12 + 4);
            c2v = sp[j * 12 + 8];
        }
        while (j < n) {
            const int jn = j + 4;
            // unconditional prefetch (sp padded; garbage never computed)
            const float4 Q0 = *(const float4*)(sp + jn * 12);
            const float4 Q1 = *(const float4*)(sp + jn * 12 + 4);
            const float  cq = sp[jn * 12 + 8];

            const float dx0 = xg0 - P0.x, dx1 = xg1 - P0.x;
            const float ax0 = P0.z * dx0, ax1 = P0.z * dx1;
            const float dy0 = yg0 - P0.y, dy1 = yg1 - P0.y;
            const float kd0 = P0.w * dy0, kd1 = P0.w * dy1;
            const float t20 = fmaf(P1.x * dy0, dy0, P1.y);
            const float t21 = fmaf(P1.x * dy1, dy1, P1.y);

            #define PXACC(R0,R1,R2,WS,DX,AX,KD,T2) { \
                const float qq = fmaf(DX, (AX) + (KD), T2); \
                const float w = EXP2(qq); \
                WS += w; \
                R0 = fmaf(w, P1.z, R0); \
                R1 = fmaf(w, P1.w, R1); \
                R2 = fmaf(w, c2v, R2); }
            PXACC(a00,a01,a02,a03, dx0,ax0,kd0,t20)
            PXACC(a10,a11,a12,a13, dx1,ax1,kd0,t20)
            PXACC(a20,a21,a22,a23, dx0,ax0,kd1,t21)
            PXACC(a30,a31,a32,a33, dx1,ax1,kd1,t21)
            #undef PXACC

            P0 = Q0; P1 = Q1; c2v = cq;
            j = jn;
        }
    }

    // ---- phase 3: combine partials, normalize, write out ----
    __syncthreads();
    if (w4 > 0) {
        const int rb = (w4 - 1) * 16;
        red[rb +  0][lane] = a00; red[rb +  1][lane] = a01;
        red[rb +  2][lane] = a02; red[rb +  3][lane] = a03;
        red[rb +  4][lane] = a10; red[rb +  5][lane] = a11;
        red[rb +  6][lane] = a12; red[rb +  7][lane] = a13;
        red[rb +  8][lane] = a20; red[rb +  9][lane] = a21;
        red[rb + 10][lane] = a22; red[rb + 11][lane] = a23;
        red[rb + 12][lane] = a30; red[rb + 13][lane] = a31;
        red[rb + 14][lane] = a32; red[rb + 15][lane] = a33;
    }
    __syncthreads();
    if (w4 == 0) {
        #pragma unroll
        for (int s = 0; s < 3; ++s) {
            const int rb = s * 16;
            a00 += red[rb +  0][lane]; a01 += red[rb +  1][lane];
            a02 += red[rb +  2][lane]; a03 += red[rb +  3][lane];
            a10 += red[rb +  4][lane]; a11 += red[rb +  5][lane];
            a12 += red[rb +  6][lane]; a13 += red[rb +  7][lane];
            a20 += red[rb +  8][lane]; a21 += red[rb +  9][lane];
            a22 += red[rb + 10][lane]; a23 += red[rb + 11][lane];
            a30 += red[rb + 12][lane]; a31 += red[rb + 13][lane];
            a32 += red[rb + 14][lane]; a33 += red[rb + 15][lane];
        }
        const float i0 = 1.f / (a03 + 1e-6f);
        const float i1 = 1.f / (a13 + 1e-6f);
        const float i2 = 1.f / (a23 + 1e-6f);
        const float i3 = 1.f / (a33 + 1e-6f);

        const int PL = HH * WW;
        float* ob = out + (b * 3) * PL + Y0 * WW + X0;
        ob[0]                    = a00 * i0;
        ob[PL]                   = a01 * i0;
        ob[2 * PL]               = a02 * i0;
        ob[8]                    = a10 * i1;
        ob[PL + 8]               = a11 * i1;
        ob[2 * PL + 8]           = a12 * i1;
        ob[8 * WW]               = a20 * i2;
        ob[PL + 8 * WW]          = a21 * i2;
        ob[2 * PL + 8 * WW]      = a22 * i2;
        ob[8 * WW + 8]           = a30 * i3;
        ob[PL + 8 * WW + 8]      = a31 * i3;
        ob[2 * PL + 8 * WW + 8]  = a32 * i3;
    }
}

extern "C" void kernel_launch(void* const* d_in, const int* in_sizes, int n_in,
                              void* d_out, int out_size, void* d_ws, size_t ws_size,
                              hipStream_t stream) {
    const float* feature = (const float*)d_in[0];   // (4,256,768) f32
    const float* proj_w  = (const float*)d_in[1];   // (36,768) f32
    const float* proj_b  = (const float*)d_in[2];   // (36,) f32
    float* params = (float*)d_ws;                   // 4096*12 f32 = 196 KB
    float* out    = (float*)d_out;                  // (4,3,256,256) f32

    param_kernel<<<NB * 256, 256, 0, stream>>>(feature, proj_w, proj_b, params);
    splat_kernel<<<NB * 256, TPB, 0, stream>>>(params, out);
}

// Round 16
// 86.934 us; speedup vs baseline: 2.7368x; 1.0690x over previous
//
#include <hip/hip_runtime.h>
#include <math.h>

#define HH 256
#define WW 256
#define NB 4
#define NG 1024      // gaussians per batch
#define DD 768
#define TH_CULL 36.0f   // cull if best-case weight exponent < -36 (err ~1e-4)
#define TPB 512         // splat threads per block (8 waves)
#define NBLK 512        // persistent-ish: 2 blocks/CU
#define IPB 2           // items ((b,tile) pairs) per block
#define CH 256          // survivors staged to LDS per chunk (12 KB)

#if __has_builtin(__builtin_amdgcn_exp2f)
#define EXP2(x) __builtin_amdgcn_exp2f(x)
#else
#define EXP2(x) exp2f(x)
#endif

// params per gaussian (12 floats, 16B aligned):
//  [0]=px [1]=py [2]=e00 [3]=e01      (float4 p0)
//  [4]=e11 [5]=lim2 [6]=c0 [7]=c1    (float4 p1)  lim2 = (rt*rsq+sqrt(TH+la))^2
//  [8]=c2 [9]=la [10..11]=pad
// weight = exp2(e00*dx^2 + e01*dx*dy + e11*dy^2 + la), e's < 0.
// cull: keep tile iff -(e00*dx^2+e01*dx*dy+e11*dy^2) <= lim2 at tile center.

__global__ __launch_bounds__(256) void param_kernel(
    const float* __restrict__ feature, const float* __restrict__ proj_w,
    const float* __restrict__ proj_b, float* __restrict__ params)
{
    __shared__ float frow[DD];
    __shared__ float gsv[36];
    const int bt  = blockIdx.x;          // 0..1023
    const int tid = threadIdx.x;

    if (tid < DD / 4) {
        ((float4*)frow)[tid] = ((const float4*)(feature + bt * DD))[tid];
    }
    __syncthreads();

    const int wave = tid >> 6, lane = tid & 63;
    for (int i = 0; i < 9; ++i) {
        const int k = wave * 9 + i;
        const float* wrow = proj_w + k * DD;
        float s = 0.f;
        #pragma unroll
        for (int j = 0; j < DD / 64; ++j)
            s = fmaf(frow[lane + j * 64], wrow[lane + j * 64], s);
        #pragma unroll
        for (int off = 32; off; off >>= 1) s += __shfl_xor(s, off, 64);
        if (lane == 0) gsv[k] = s + proj_b[k];
    }
    __syncthreads();

    if (tid < 4) {
        const float* g = gsv + tid * 9;
        const float px = g[0], py = g[1];
        const float sx = expf(g[2]), sy = expf(g[3]);
        const float sx2 = sx * sx, sy2 = sy * sy;
        const float cs = cosf(g[4]), sn = sinf(g[4]);
        const float c00 = cs * cs * sx2 + sn * sn * sy2 + 1e-6f;
        const float c01 = cs * sn * (sx2 - sy2);
        const float c11 = sn * sn * sx2 + cs * cs * sy2 + 1e-6f;
        const float det = c00 * c11 - c01 * c01;
        const float i00 = c11 / det, i01 = -c01 / det, i11 = c00 / det;
        const float F = 0.72134752044448170368f;   // 0.5 * log2(e)
        const float e00 = -F * i00;
        const float e01 = -2.f * F * i01;
        const float e11 = -F * i11;
        const float la = -log2f(1.f + expf(-g[5]));   // log2(sigmoid)
        const float rsq = sqrtf(-(e00 + e11));
        const float rt  = 0.08318903f;   // (2/255)*7.5*sqrt(2): tile circle radius
        const float ta  = fmaxf(TH_CULL + la, 0.f);
        const float lim = rt * rsq + sqrtf(ta);
        float* o = params + (bt * 4 + tid) * 12;
        o[0] = px;  o[1] = py;  o[2] = e00;       o[3] = e01;
        o[4] = e11; o[5] = lim * lim; o[6] = g[6]; o[7] = g[7];
        o[8] = g[8]; o[9] = la; o[10] = 0.f; o[11] = 0.f;
    }
}

// 512 blocks x 512 thr (8 waves), 2 items ((b,tile)) per block, sequential.
// item = s*NBLK + blk; b = item&3; tl = ((item>>2)*73)&255 (scramble hotness).
// Per item: cull 1024 gaussians (2 rounds x 512, 2-load no-sqrt test) ->
// LDS slist; chunks of 256 staged to LDS; each WAVE covers the 16x16 tile
// (lane = 2x2 px), 8 waves stride the chunk by 8 with a 2-deep software
// pipeline; LDS reduce 8 waves -> wave0 normalizes and writes out.
__global__ __launch_bounds__(TPB) void splat_kernel(
    const float* __restrict__ params, float* __restrict__ out)
{
    __shared__ int   slist[NG];            // 4 KB
    __shared__ float sp[CH * 12 + 96];     // 12.4 KB (+pad for prefetch over-read)
    __shared__ float red[112][64];         // 28 KB: 7 waves x 16 vals
    __shared__ int   scount;

    const int blk  = blockIdx.x;
    const int tid  = threadIdx.x;
    const int lane = tid & 63;
    const int w8   = tid >> 6;             // wave id 0..7
    const int xl   = lane & 7, yl = lane >> 3;
    const float s2 = 2.f / 255.f;

    for (int s = 0; s < IPB; ++s) {
        const int item = s * NBLK + blk;
        const int b    = item & 3;
        const int tl   = ((item >> 2) * 73) & 255;   // scramble tile order
        const int ty   = tl >> 4, tx = tl & 15;

        if (tid == 0) scount = 0;
        __syncthreads();

        const float cx = -1.f + s2 * ((float)(tx * 16) + 7.5f);
        const float cy = -1.f + s2 * ((float)(ty * 16) + 7.5f);
        const float* gp = params + b * NG * 12;

        // ---- cull: 2 rounds x 512 threads, 2 loads, no sqrt ----
        for (int k = 0; k < 2; ++k) {
            const int gi = k * TPB + tid;
            const float4 p0 = *(const float4*)(gp + gi * 12);      // px,py,e00,e01
            const float4 p1 = *(const float4*)(gp + gi * 12 + 4);  // e11,lim2,c0,c1
            const float dx = cx - p0.x, dy = cy - p0.y;
            const float qd = -fmaf(p0.z * dx, dx, fmaf(p0.w * dx, dy, p1.x * dy * dy));
            const bool keep = (qd <= p1.y);
            const unsigned long long mask = __ballot(keep);
            int base = 0;
            if (lane == 0 && mask) base = atomicAdd(&scount, (int)__popcll(mask));
            base = __shfl(base, 0, 64);
            if (keep) {
                const int off = (int)__popcll(mask & ((1ull << lane) - 1ull));
                slist[base + off] = gi;
            }
        }
        __syncthreads();
        const int cnt = scount;

        // ---- splat: 2x2 px per lane, 8 waves stride 8 ----
        const int X0 = tx * 16 + xl, Y0 = ty * 16 + yl;
        const float xg0 = -1.f + s2 * (float)X0;
        const float xg1 = -1.f + s2 * (float)(X0 + 8);
        const float yg0 = -1.f + s2 * (float)Y0;
        const float yg1 = -1.f + s2 * (float)(Y0 + 8);

        float a00=0.f,a01=0.f,a02=0.f,a03=0.f;
        float a10=0.f,a11=0.f,a12=0.f,a13=0.f;
        float a20=0.f,a21=0.f,a22=0.f,a23=0.f;
        float a30=0.f,a31=0.f,a32=0.f,a33=0.f;

        for (int cb = 0; cb < cnt; cb += CH) {
            const int n = min(CH, cnt - cb);
            __syncthreads();                 // sp free / slist ready
            for (int i = tid; i < n * 3; i += TPB) {
                const int gl = i / 3;
                const int wd = i - gl * 3;
                const int gi = slist[cb + gl];
                *(float4*)(sp + gl * 12 + wd * 4) =
                    *(const float4*)(gp + gi * 12 + wd * 4);
            }
            __syncthreads();                 // chunk staged

            // 2-deep software pipeline: prefetch j+8 while computing j.
            int j = w8;
            float4 P0, P1; float2 P2;
            if (j < n) {
                P0 = *(const float4*)(sp + j * 12);
                P1 = *(const float4*)(sp + j * 12 + 4);
                P2 = *(const float2*)(sp + j * 12 + 8);   // c2, la
            }
            while (j < n) {
                const int jn = j + 8;
                const float4 Q0 = *(const float4*)(sp + jn * 12);
                const float4 Q1 = *(const float4*)(sp + jn * 12 + 4);
                const float2 Q2 = *(const float2*)(sp + jn * 12 + 8);

                const float dx0 = xg0 - P0.x, dx1 = xg1 - P0.x;
                const float ax0 = P0.z * dx0, ax1 = P0.z * dx1;
                const float dy0 = yg0 - P0.y, dy1 = yg1 - P0.y;
                const float kd0 = P0.w * dy0, kd1 = P0.w * dy1;
                const float t20 = fmaf(P1.x * dy0, dy0, P2.y);
                const float t21 = fmaf(P1.x * dy1, dy1, P2.y);

                #define PXACC(R0,R1,R2,WS,DX,AX,KD,T2) { \
                    const float qq = fmaf(DX, (AX) + (KD), T2); \
                    const float w = EXP2(qq); \
                    WS += w; \
                    R0 = fmaf(w, P1.z, R0); \
                    R1 = fmaf(w, P1.w, R1); \
                    R2 = fmaf(w, P2.x, R2); }
                PXACC(a00,a01,a02,a03, dx0,ax0,kd0,t20)
                PXACC(a10,a11,a12,a13, dx1,ax1,kd0,t20)
                PXACC(a20,a21,a22,a23, dx0,ax0,kd1,t21)
                PXACC(a30,a31,a32,a33, dx1,ax1,kd1,t21)
                #undef PXACC

                P0 = Q0; P1 = Q1; P2 = Q2;
                j = jn;
            }
        }

        // ---- reduce 8 waves -> wave0, normalize, write ----
        __syncthreads();
        if (w8 > 0) {
            const int rb = (w8 - 1) * 16;
            red[rb +  0][lane] = a00; red[rb +  1][lane] = a01;
            red[rb +  2][lane] = a02; red[rb +  3][lane] = a03;
            red[rb +  4][lane] = a10; red[rb +  5][lane] = a11;
            red[rb +  6][lane] = a12; red[rb +  7][lane] = a13;
            red[rb +  8][lane] = a20; red[rb +  9][lane] = a21;
            red[rb + 10][lane] = a22; red[rb + 11][lane] = a23;
            red[rb + 12][lane] = a30; red[rb + 13][lane] = a31;
            red[rb + 14][lane] = a32; red[rb + 15][lane] = a33;
        }
        __syncthreads();
        if (w8 == 0) {
            #pragma unroll
            for (int r = 0; r < 7; ++r) {
                const int rb = r * 16;
                a00 += red[rb +  0][lane]; a01 += red[rb +  1][lane];
                a02 += red[rb +  2][lane]; a03 += red[rb +  3][lane];
                a10 += red[rb +  4][lane]; a11 += red[rb +  5][lane];
                a12 += red[rb +  6][lane]; a13 += red[rb +  7][lane];
                a20 += red[rb +  8][lane]; a21 += red[rb +  9][lane];
                a22 += red[rb + 10][lane]; a23 += red[rb + 11][lane];
                a30 += red[rb + 12][lane]; a31 += red[rb + 13][lane];
                a32 += red[rb + 14][lane]; a33 += red[rb + 15][lane];
            }
            const float i0 = 1.f / (a03 + 1e-6f);
            const float i1 = 1.f / (a13 + 1e-6f);
            const float i2 = 1.f / (a23 + 1e-6f);
            const float i3 = 1.f / (a33 + 1e-6f);

            const int PL = HH * WW;
            float* ob = out + (b * 3) * PL + Y0 * WW + X0;
            ob[0]                    = a00 * i0;
            ob[PL]                   = a01 * i0;
            ob[2 * PL]               = a02 * i0;
            ob[8]                    = a10 * i1;
            ob[PL + 8]               = a11 * i1;
            ob[2 * PL + 8]           = a12 * i1;
            ob[8 * WW]               = a20 * i2;
            ob[PL + 8 * WW]          = a21 * i2;
            ob[2 * PL + 8 * WW]      = a22 * i2;
            ob[8 * WW + 8]           = a30 * i3;
            ob[PL + 8 * WW + 8]      = a31 * i3;
            ob[2 * PL + 8 * WW + 8]  = a32 * i3;
        }
        __syncthreads();   // slist/scount/sp reuse safe for next item
    }
}

extern "C" void kernel_launch(void* const* d_in, const int* in_sizes, int n_in,
                              void* d_out, int out_size, void* d_ws, size_t ws_size,
                              hipStream_t stream) {
    const float* feature = (const float*)d_in[0];   // (4,256,768) f32
    const float* proj_w  = (const float*)d_in[1];   // (36,768) f32
    const float* proj_b  = (const float*)d_in[2];   // (36,) f32
    float* params = (float*)d_ws;                   // 4096*12 f32 = 196 KB
    float* out    = (float*)d_out;                  // (4,3,256,256) f32

    param_kernel<<<NB * 256, 256, 0, stream>>>(feature, proj_w, proj_b, params);
    splat_kernel<<<NBLK, TPB, 0, stream>>>(params, out);
}